// Round 5
// baseline (80.504 us; speedup 1.0000x reference)
//
#include <hip/hip_runtime.h>

using short8 = __attribute__((ext_vector_type(8))) short;
using f32x4  = __attribute__((ext_vector_type(4))) float;
using u32x4  = __attribute__((ext_vector_type(4))) unsigned int;

#define NC 256
#define NW 64
#define ND 21
#define HW 3072              /* 48*64, per-channel stride in floats */
#define H2 24

static const size_t WS_F2   = (size_t)384 * 32 * 1024;   /* f2 blobs only  */
static const size_t WS_FULL = (size_t)768 * 32 * 1024;   /* f2 + f1 blobs  */

__device__ __forceinline__ int imax(int a, int b) { return a > b ? a : b; }
__device__ __forceinline__ int imin(int a, int b) { return a < b ? a : b; }

__device__ __forceinline__ unsigned int cvtpk(float a, float b) {
    unsigned int r;
    asm("v_cvt_pk_bf16_f32 %0, %1, %2" : "=v"(r) : "v"(a), "v"(b));
    return r;
}

// byte offset into a [64 rows][256 ch] bf16 tile, XOR-swizzled (verified R1-R4)
__device__ __forceinline__ unsigned int swz_off(int row, int cb) {
    return (row << 9) + ((cb << 1) ^ (((row >> 1) & 7) << 4));
}

// barrier draining LDS ops only — global loads/stores stay in flight
#define BARRIER() asm volatile("s_waitcnt lgkmcnt(0)\n\ts_barrier" ::: "memory")

struct Stage { float2 v[16]; };   // one f32 row slice: 128 B/thread

__device__ __forceinline__ void stage_issue(Stage& st, const float* rowbase, int xp, int cg) {
    const float* s = rowbase + 2 * xp;
    #pragma unroll
    for (int cc = 0; cc < 2; ++cc)
        #pragma unroll
        for (int e = 0; e < 4; ++e) {
            int c = cc * 128 + cg * 8 + 2 * e;
            st.v[cc * 8 + 2 * e    ] = *reinterpret_cast<const float2*>(s + (size_t)c * HW);
            st.v[cc * 8 + 2 * e + 1] = *reinterpret_cast<const float2*>(s + (size_t)(c + 1) * HW);
        }
}

__device__ __forceinline__ void stage_pack(const Stage& st, int cc, u32x4& p0, u32x4& p1) {
    #pragma unroll
    for (int e = 0; e < 4; ++e) {
        float2 va = st.v[cc * 8 + 2 * e];
        float2 vb = st.v[cc * 8 + 2 * e + 1];
        p0[e] = cvtpk(va.x, vb.x);
        p1[e] = cvtpk(va.y, vb.y);
    }
}

__device__ __forceinline__ void stage_commit_lds(const Stage& st, unsigned short* lds, int xp, int cg) {
    #pragma unroll
    for (int cc = 0; cc < 2; ++cc) {
        int c0 = cc * 128 + cg * 8;
        u32x4 p0, p1;
        stage_pack(st, cc, p0, p1);
        *reinterpret_cast<u32x4*>(reinterpret_cast<char*>(lds) + swz_off(2 * xp,     c0)) = p0;
        *reinterpret_cast<u32x4*>(reinterpret_cast<char*>(lds) + swz_off(2 * xp + 1, c0)) = p1;
    }
}

__device__ __forceinline__ void stage_commit_glob(const Stage& st, unsigned short* blob, int xp, int cg) {
    #pragma unroll
    for (int cc = 0; cc < 2; ++cc) {
        int c0 = cc * 128 + cg * 8;
        u32x4 p0, p1;
        stage_pack(st, cc, p0, p1);
        *reinterpret_cast<u32x4*>(reinterpret_cast<char*>(blob) + swz_off(2 * xp,     c0)) = p0;
        *reinterpret_cast<u32x4*>(reinterpret_cast<char*>(blob) + swz_off(2 * xp + 1, c0)) = p1;
    }
}

// ---- pre-pass: f32 [c][x] row -> bf16 blob [x][c] swizzled (32 KB each) ----
// XCD-aligned: blob (b*48+y) is produced by a WG on XCD b (bid%8 == b), the
// same XCD the main-kernel swizzle assigns its consumers to -> blob reads
// become local-L2 hits instead of cross-XCD misses.
// grid 384: f2 blobs 0..383.  grid 768: + f1 blobs 384..767.
__global__ __launch_bounds__(512, 4) void prep_kernel(const float* __restrict__ f1,
                                                      const float* __restrict__ f2,
                                                      unsigned short* __restrict__ ws) {
    int bid = blockIdx.x;
    int xcd = bid & 7;             // empirical: dispatch round-robins bid%8 -> XCD
    int m   = bid >> 3;            // [0,96)
    const float* src;
    int rid, blob_id;
    if (m < 48) { rid = xcd * 48 + m;        blob_id = rid;       src = f2; }
    else        { rid = xcd * 48 + (m - 48); blob_id = 384 + rid; src = f1; }
    int b = rid / 48, y = rid - b * 48;
    const float* row = src + (size_t)b * NC * HW + (size_t)y * NW;
    unsigned short* blob = ws + ((size_t)blob_id << 14);
    int tid = threadIdx.x, xp = tid & 31, cg = tid >> 5;
    Stage st;
    stage_issue(st, row, xp, cg);
    stage_commit_glob(st, blob, xp, cg);
}

// ---- linear blob <-> LDS copy: 64 B/thread over 512 threads = 32 KB ----
struct BStage { u32x4 q[4]; };

__device__ __forceinline__ void bstage_issue(BStage& st, const unsigned short* blob, int tid) {
    const u32x4* p = reinterpret_cast<const u32x4*>(blob) + tid;
    st.q[0] = p[0]; st.q[1] = p[512]; st.q[2] = p[1024]; st.q[3] = p[1536];
}
__device__ __forceinline__ void bstage_commit(const BStage& st, unsigned short* lds, int tid) {
    u32x4* p = reinterpret_cast<u32x4*>(lds) + tid;
    p[0] = st.q[0]; p[512] = st.q[1]; p[1024] = st.q[2]; p[1536] = st.q[3];
}

// ---- main kernel: WG = (b, py, uy, hf); single y-row; 40.0 KB LDS -> 4 WG/CU ----
template<bool ABLOB>
__global__ __launch_bounds__(512, 8) void corr_main3(const float* __restrict__ f1,
                                                     const unsigned short* __restrict__ ws,
                                                     float* __restrict__ out) {
    __shared__ __align__(16) unsigned short buf[16384];   // 32 KB: A (prologue) then B rows
    __shared__ float Sl[64 * 32];                         // 8 KB, additive-swizzled

    int bid = blockIdx.x;
    // bijective XCD swizzle: 768 = 8*96; XCD k serves batch b=k only
    int swz = (bid & 7) * 96 + (bid >> 3);
    int hf  = swz & 1;
    int uy  = (swz >> 1) % 24;
    int g   = swz / 48;            // b*2 + py
    int py  = g & 1, b = g >> 1;
    int y   = 2 * uy + py;

    int tid = threadIdx.x, lane = tid & 63, w = tid >> 6;
    int px = w & 1, m0 = ((w >> 1) & 1) * 16, n0 = ((w >> 2) & 1) * 16;
    int l15 = lane & 15, g4 = lane >> 4;

    float* outb = out + (size_t)b * 441 * HW + (size_t)y * NW;   // + d*HW + x

    int ilo_h = hf ? 11 : 0, ihi_h = hf ? 20 : 10;
    int ilo   = imax(ilo_h, 10 - uy);
    int ihi   = imin(ihi_h, 33 - uy);

    // zero-fill output rows whose displaced source row is out of bounds
    for (int i = ilo_h; i <= ihi_h; ++i) {
        if (i >= ilo && i <= ihi) continue;
        for (int t = tid; t < ND * 64; t += 512) {
            int j = t >> 6, x = t & 63;
            outb[(size_t)(i * ND + j) * HW + x] = 0.f;
        }
    }
    if (ilo > ihi) return;

    // ---- prologue: A row -> buf -> per-wave fragments ----
    if (ABLOB) {
        BStage a0;
        bstage_issue(a0, ws + ((size_t)(384 + b * 48 + y) << 14), tid);
        bstage_commit(a0, buf, tid);
    } else {
        Stage s;
        stage_issue(s, f1 + (size_t)b * NC * HW + (size_t)y * NW, tid & 31, tid >> 5);
        stage_commit_lds(s, buf, tid & 31, tid >> 5);
    }
    BARRIER();                                   // A ready
    short8 afrag[8];
    int arow = 2 * (m0 + l15) + px;
    #pragma unroll
    for (int kk = 0; kk < 8; ++kk)
        afrag[kk] = *reinterpret_cast<const short8*>(
            reinterpret_cast<const char*>(buf) + swz_off(arow, kk * 32 + g4 * 8));
    BStage bst;
    bstage_issue(bst, ws + ((size_t)(b * 48 + 2 * (uy + ilo - 10) + py) << 14), tid);
    BARRIER();                                   // afrag reads done; buf reusable

    int brow = 2 * (n0 + l15) + px;
    int srow = 2 * (m0 + g4 * 4) + px;           // + 2*rr
    int scol = n0 + l15;

    for (int i = ilo; i <= ihi; ++i) {
        bstage_commit(bst, buf, tid);            // write-late (waits only own loads)
        if (i < ihi)                              // issue-early for next row (local-L2)
            bstage_issue(bst, ws + ((size_t)(b * 48 + 2 * (uy + i + 1 - 10) + py) << 14), tid);
        BARRIER();   // buf ready; also orders prev gather ds_reads before S overwrite

        f32x4 acc = {0.f, 0.f, 0.f, 0.f};
        #pragma unroll
        for (int kk = 0; kk < 8; ++kk) {
            short8 bf = *reinterpret_cast<const short8*>(
                reinterpret_cast<const char*>(buf) + swz_off(brow, kk * 32 + g4 * 8));
            acc = __builtin_amdgcn_mfma_f32_16x16x32_bf16(afrag[kk], bf, acc, 0, 0, 0);
        }
        // C/D: col = lane&15 -> vx, row = g4*4 + rr -> ux (verified R1-R4)
        // S swizzle: idx = row*32 + ((col+row)&31); write banks spread by 8*g4,
        // gather banks (3u+j) mod 32 -> exact 2-way (free) on both sides
        #pragma unroll
        for (int rr = 0; rr < 4; ++rr) {
            int row = srow + 2 * rr;
            Sl[(row << 5) | ((scol + row) & 31)] = acc[rr] * (1.f / 256.f);
        }
        BARRIER();   // S ready; B-frag reads retired

        // banded gather: out[x, j] = S[x, x/2 + j - 10]; coalesced 256 B stores
        for (int t = tid; t < ND * 64; t += 512) {
            int j = t >> 6, x = t & 63;
            int vx = (x >> 1) + j - 10;
            float v = ((unsigned)vx < 32u) ? Sl[(x << 5) | ((vx + x) & 31)] : 0.f;
            outb[(size_t)(i * ND + j) * HW + x] = v;
        }
    }
}

// ---- fallback (round-1 structure, known good, no workspace) ----
__global__ __launch_bounds__(512, 4) void corr_fallback(const float* __restrict__ f1,
                                                        const float* __restrict__ f2,
                                                        float* __restrict__ out) {
    __shared__ __align__(16) unsigned short Alds[64 * 256];
    __shared__ __align__(16) unsigned short Blds[64 * 256];
    __shared__ float Slds[64][33];

    int bid = blockIdx.x;
    int swz = (bid & 7) * 48 + (bid >> 3);
    int uy = swz % 24;
    int g  = swz / 24;
    int py = g & 1;
    int b  = g >> 1;
    int y  = 2 * uy + py;

    int tid = threadIdx.x, lane = tid & 63, w = tid >> 6;
    int xp = tid & 31, cg = tid >> 5;

    const float* f1row  = f1 + (size_t)b * NC * HW + (size_t)y * NW;
    const float* f2base = f2 + (size_t)b * NC * HW;
    float* outb = out + (size_t)b * 441 * HW + (size_t)y * NW;

    for (int i = 0; i < ND; ++i) {
        int vy = uy + i - 10;
        if (vy >= 0 && vy < H2) continue;
        for (int t = tid; t < ND * 64; t += 512) {
            int j = t >> 6, x = t & 63;
            outb[(size_t)(i * ND + j) * HW + x] = 0.f;
        }
    }

    Stage st;
    stage_issue(st, f1row, xp, cg);
    stage_commit_lds(st, Alds, xp, cg);
    __syncthreads();

    int px  = w & 1;
    int m0  = ((w >> 1) & 1) * 16;
    int n0  = ((w >> 2) & 1) * 16;
    int l15 = lane & 15;
    int kgr = (lane >> 4) * 8;

    short8 afrag[8];
    int arow = 2 * (m0 + l15) + px;
    #pragma unroll
    for (int kk = 0; kk < 8; ++kk)
        afrag[kk] = *reinterpret_cast<const short8*>(
            reinterpret_cast<const char*>(Alds) + swz_off(arow, kk * 32 + kgr));

    int brow = 2 * (n0 + l15) + px;
    int srow = 2 * (m0 + (lane >> 4) * 4) + px;
    int scol = n0 + l15;

    for (int vy = uy - 10; vy <= uy + 10; ++vy) {
        if (vy < 0 || vy >= H2) continue;
        int i  = vy - uy + 10;
        int y2 = 2 * vy + py;
        __syncthreads();
        stage_issue(st, f2base + (size_t)y2 * NW, xp, cg);
        stage_commit_lds(st, Blds, xp, cg);
        __syncthreads();

        f32x4 acc = {0.f, 0.f, 0.f, 0.f};
        #pragma unroll
        for (int kk = 0; kk < 8; ++kk) {
            short8 bfrag = *reinterpret_cast<const short8*>(
                reinterpret_cast<const char*>(Blds) + swz_off(brow, kk * 32 + kgr));
            acc = __builtin_amdgcn_mfma_f32_16x16x32_bf16(afrag[kk], bfrag, acc, 0, 0, 0);
        }
        #pragma unroll
        for (int r = 0; r < 4; ++r)
            Slds[srow + 2 * r][scol] = acc[r] * (1.f / 256.f);
        __syncthreads();

        for (int t = tid; t < ND * 64; t += 512) {
            int j = t >> 6, x = t & 63;
            int vx = (x >> 1) + j - 10;
            float v = ((unsigned)vx < 32u) ? Slds[x][vx] : 0.f;
            outb[(size_t)(i * ND + j) * HW + x] = v;
        }
    }
}

extern "C" void kernel_launch(void* const* d_in, const int* in_sizes, int n_in,
                              void* d_out, int out_size, void* d_ws, size_t ws_size,
                              hipStream_t stream) {
    const float* in1 = (const float*)d_in[0];
    const float* in2 = (const float*)d_in[1];
    float* o = (float*)d_out;
    if (ws_size >= WS_FULL) {
        hipLaunchKernelGGL(prep_kernel, dim3(768), dim3(512), 0, stream, in1, in2, (unsigned short*)d_ws);
        hipLaunchKernelGGL(corr_main3<true>, dim3(768), dim3(512), 0, stream,
                           in1, (const unsigned short*)d_ws, o);
    } else if (ws_size >= WS_F2) {
        hipLaunchKernelGGL(prep_kernel, dim3(384), dim3(512), 0, stream, in1, in2, (unsigned short*)d_ws);
        hipLaunchKernelGGL(corr_main3<false>, dim3(768), dim3(512), 0, stream,
                           in1, (const unsigned short*)d_ws, o);
    } else {
        hipLaunchKernelGGL(corr_fallback, dim3(384), dim3(512), 0, stream, in1, in2, o);
    }
}

// Round 6
// 41.886 us; speedup vs baseline: 1.9220x; 1.9220x over previous
//
#include <hip/hip_runtime.h>

using short8 = __attribute__((ext_vector_type(8))) short;
using f32x4  = __attribute__((ext_vector_type(4))) float;
using u32x4  = __attribute__((ext_vector_type(4))) unsigned int;

#define NC 256
#define NW 64
#define ND 21
#define HW 3072              /* 48*64, per-channel stride in floats */
#define H2 24

static const size_t WS_F2   = (size_t)384 * 32 * 1024;   /* f2 blobs only  */
static const size_t WS_FULL = (size_t)768 * 32 * 1024;   /* f2 + f1 blobs  */

__device__ __forceinline__ int imax(int a, int b) { return a > b ? a : b; }
__device__ __forceinline__ int imin(int a, int b) { return a < b ? a : b; }

__device__ __forceinline__ unsigned int cvtpk(float a, float b) {
    unsigned int r;
    asm("v_cvt_pk_bf16_f32 %0, %1, %2" : "=v"(r) : "v"(a), "v"(b));
    return r;
}

// byte offset into a [64 rows][256 ch] bf16 tile, XOR-swizzled (verified R1-R4)
__device__ __forceinline__ unsigned int swz_off(int row, int cb) {
    return (row << 9) + ((cb << 1) ^ (((row >> 1) & 7) << 4));
}

// barrier draining LDS ops only — global loads/stores stay in flight
#define BARRIER() asm volatile("s_waitcnt lgkmcnt(0)\n\ts_barrier" ::: "memory")

struct Stage { float2 v[16]; };   // one f32 row slice: 128 B/thread

__device__ __forceinline__ void stage_issue(Stage& st, const float* rowbase, int xp, int cg) {
    const float* s = rowbase + 2 * xp;
    #pragma unroll
    for (int cc = 0; cc < 2; ++cc)
        #pragma unroll
        for (int e = 0; e < 4; ++e) {
            int c = cc * 128 + cg * 8 + 2 * e;
            st.v[cc * 8 + 2 * e    ] = *reinterpret_cast<const float2*>(s + (size_t)c * HW);
            st.v[cc * 8 + 2 * e + 1] = *reinterpret_cast<const float2*>(s + (size_t)(c + 1) * HW);
        }
}

__device__ __forceinline__ void stage_pack(const Stage& st, int cc, u32x4& p0, u32x4& p1) {
    #pragma unroll
    for (int e = 0; e < 4; ++e) {
        float2 va = st.v[cc * 8 + 2 * e];
        float2 vb = st.v[cc * 8 + 2 * e + 1];
        p0[e] = cvtpk(va.x, vb.x);
        p1[e] = cvtpk(va.y, vb.y);
    }
}

__device__ __forceinline__ void stage_commit_lds(const Stage& st, unsigned short* lds, int xp, int cg) {
    #pragma unroll
    for (int cc = 0; cc < 2; ++cc) {
        int c0 = cc * 128 + cg * 8;
        u32x4 p0, p1;
        stage_pack(st, cc, p0, p1);
        *reinterpret_cast<u32x4*>(reinterpret_cast<char*>(lds) + swz_off(2 * xp,     c0)) = p0;
        *reinterpret_cast<u32x4*>(reinterpret_cast<char*>(lds) + swz_off(2 * xp + 1, c0)) = p1;
    }
}

__device__ __forceinline__ void stage_commit_glob(const Stage& st, unsigned short* blob, int xp, int cg) {
    #pragma unroll
    for (int cc = 0; cc < 2; ++cc) {
        int c0 = cc * 128 + cg * 8;
        u32x4 p0, p1;
        stage_pack(st, cc, p0, p1);
        *reinterpret_cast<u32x4*>(reinterpret_cast<char*>(blob) + swz_off(2 * xp,     c0)) = p0;
        *reinterpret_cast<u32x4*>(reinterpret_cast<char*>(blob) + swz_off(2 * xp + 1, c0)) = p1;
    }
}

// ---- pre-pass: f32 [c][x] row -> bf16 blob [x][c] swizzled (32 KB each) ----
// XCD-aligned: blob (b*48+y) is produced on XCD b, same as its consumers.
// grid 384: f2 blobs 0..383.  grid 768: + f1 blobs 384..767.
__global__ __launch_bounds__(512, 4) void prep_kernel(const float* __restrict__ f1,
                                                      const float* __restrict__ f2,
                                                      unsigned short* __restrict__ ws) {
    int bid = blockIdx.x;
    int xcd = bid & 7;             // empirical: dispatch round-robins bid%8 -> XCD
    int m   = bid >> 3;            // [0,96)
    const float* src;
    int rid, blob_id;
    if (m < 48) { rid = xcd * 48 + m;        blob_id = rid;       src = f2; }
    else        { rid = xcd * 48 + (m - 48); blob_id = 384 + rid; src = f1; }
    int b = rid / 48, y = rid - b * 48;
    const float* row = src + (size_t)b * NC * HW + (size_t)y * NW;
    unsigned short* blob = ws + ((size_t)blob_id << 14);
    int tid = threadIdx.x, xp = tid & 31, cg = tid >> 5;
    Stage st;
    stage_issue(st, row, xp, cg);
    stage_commit_glob(st, blob, xp, cg);
}

// ---- linear blob <-> LDS copy: 64 B/thread over 512 threads = 32 KB ----
struct BStage { u32x4 q[4]; };

__device__ __forceinline__ void bstage_issue(BStage& st, const unsigned short* blob, int tid) {
    const u32x4* p = reinterpret_cast<const u32x4*>(blob) + tid;
    st.q[0] = p[0]; st.q[1] = p[512]; st.q[2] = p[1024]; st.q[3] = p[1536];
}
__device__ __forceinline__ void bstage_commit(const BStage& st, unsigned short* lds, int tid) {
    u32x4* p = reinterpret_cast<u32x4*>(lds) + tid;
    p[0] = st.q[0]; p[512] = st.q[1]; p[1024] = st.q[2]; p[1536] = st.q[3];
}

// ---- main kernel: WG = (b, py, uy, hf); single y-row; 40 KB LDS; 3 WG/CU ----
// launch_bounds (512,6): VGPR budget ~85 — R5's (512,8) capped at 32 VGPR and
// spilled afrag+BStage to scratch (FETCH 18->130 MB). Residency = min(LDS 4,
// VGPR 3) = 3 WG/CU; grid 768 <= 768 slots -> one dispatch round.
template<bool ABLOB>
__global__ __launch_bounds__(512, 6) void corr_main3(const float* __restrict__ f1,
                                                     const unsigned short* __restrict__ ws,
                                                     float* __restrict__ out) {
    __shared__ __align__(16) unsigned short buf[16384];   // 32 KB: A (prologue) then B rows
    __shared__ float Sl[64 * 32];                         // 8 KB, additive-swizzled

    int bid = blockIdx.x;
    // bijective XCD swizzle: 768 = 8*96; XCD k serves batch b=k only
    int swz = (bid & 7) * 96 + (bid >> 3);
    int hf  = swz & 1;
    int uy  = (swz >> 1) % 24;
    int g   = swz / 48;            // b*2 + py
    int py  = g & 1, b = g >> 1;
    int y   = 2 * uy + py;

    int tid = threadIdx.x, lane = tid & 63, w = tid >> 6;
    int px = w & 1, m0 = ((w >> 1) & 1) * 16, n0 = ((w >> 2) & 1) * 16;
    int l15 = lane & 15, g4 = lane >> 4;

    float* outb = out + (size_t)b * 441 * HW + (size_t)y * NW;   // + d*HW + x

    int ilo_h = hf ? 11 : 0, ihi_h = hf ? 20 : 10;
    int ilo   = imax(ilo_h, 10 - uy);
    int ihi   = imin(ihi_h, 33 - uy);

    // zero-fill output rows whose displaced source row is out of bounds
    for (int i = ilo_h; i <= ihi_h; ++i) {
        if (i >= ilo && i <= ihi) continue;
        for (int t = tid; t < ND * 64; t += 512) {
            int j = t >> 6, x = t & 63;
            outb[(size_t)(i * ND + j) * HW + x] = 0.f;
        }
    }
    if (ilo > ihi) return;

    // ---- prologue: A row -> buf -> per-wave fragments ----
    if (ABLOB) {
        BStage a0;
        bstage_issue(a0, ws + ((size_t)(384 + b * 48 + y) << 14), tid);
        bstage_commit(a0, buf, tid);
    } else {
        Stage s;
        stage_issue(s, f1 + (size_t)b * NC * HW + (size_t)y * NW, tid & 31, tid >> 5);
        stage_commit_lds(s, buf, tid & 31, tid >> 5);
    }
    BARRIER();                                   // A ready
    short8 afrag[8];
    int arow = 2 * (m0 + l15) + px;
    #pragma unroll
    for (int kk = 0; kk < 8; ++kk)
        afrag[kk] = *reinterpret_cast<const short8*>(
            reinterpret_cast<const char*>(buf) + swz_off(arow, kk * 32 + g4 * 8));
    BStage bst;
    bstage_issue(bst, ws + ((size_t)(b * 48 + 2 * (uy + ilo - 10) + py) << 14), tid);
    BARRIER();                                   // afrag reads done; buf reusable

    int brow = 2 * (n0 + l15) + px;
    int srow = 2 * (m0 + g4 * 4) + px;           // + 2*rr
    int scol = n0 + l15;

    for (int i = ilo; i <= ihi; ++i) {
        bstage_commit(bst, buf, tid);            // write-late (waits only own loads)
        if (i < ihi)                              // issue-early for next row (local-L2)
            bstage_issue(bst, ws + ((size_t)(b * 48 + 2 * (uy + i + 1 - 10) + py) << 14), tid);
        BARRIER();   // buf ready; also orders prev gather ds_reads before S overwrite

        f32x4 acc = {0.f, 0.f, 0.f, 0.f};
        #pragma unroll
        for (int kk = 0; kk < 8; ++kk) {
            short8 bf = *reinterpret_cast<const short8*>(
                reinterpret_cast<const char*>(buf) + swz_off(brow, kk * 32 + g4 * 8));
            acc = __builtin_amdgcn_mfma_f32_16x16x32_bf16(afrag[kk], bf, acc, 0, 0, 0);
        }
        // C/D: col = lane&15 -> vx, row = g4*4 + rr -> ux (verified R1-R4)
        // S swizzle: idx = row*32 + ((col+row)&31); write banks spread by 8*g4,
        // gather banks (3u+j) mod 32 -> exact 2-way (free) on both sides
        #pragma unroll
        for (int rr = 0; rr < 4; ++rr) {
            int row = srow + 2 * rr;
            Sl[(row << 5) | ((scol + row) & 31)] = acc[rr] * (1.f / 256.f);
        }
        BARRIER();   // S ready; B-frag reads retired

        // banded gather: out[x, j] = S[x, x/2 + j - 10]; coalesced 256 B stores
        for (int t = tid; t < ND * 64; t += 512) {
            int j = t >> 6, x = t & 63;
            int vx = (x >> 1) + j - 10;
            float v = ((unsigned)vx < 32u) ? Sl[(x << 5) | ((vx + x) & 31)] : 0.f;
            outb[(size_t)(i * ND + j) * HW + x] = v;
        }
    }
}

// ---- fallback (round-1 structure, known good, no workspace) ----
__global__ __launch_bounds__(512, 4) void corr_fallback(const float* __restrict__ f1,
                                                        const float* __restrict__ f2,
                                                        float* __restrict__ out) {
    __shared__ __align__(16) unsigned short Alds[64 * 256];
    __shared__ __align__(16) unsigned short Blds[64 * 256];
    __shared__ float Slds[64][33];

    int bid = blockIdx.x;
    int swz = (bid & 7) * 48 + (bid >> 3);
    int uy = swz % 24;
    int g  = swz / 24;
    int py = g & 1;
    int b  = g >> 1;
    int y  = 2 * uy + py;

    int tid = threadIdx.x, lane = tid & 63, w = tid >> 6;
    int xp = tid & 31, cg = tid >> 5;

    const float* f1row  = f1 + (size_t)b * NC * HW + (size_t)y * NW;
    const float* f2base = f2 + (size_t)b * NC * HW;
    float* outb = out + (size_t)b * 441 * HW + (size_t)y * NW;

    for (int i = 0; i < ND; ++i) {
        int vy = uy + i - 10;
        if (vy >= 0 && vy < H2) continue;
        for (int t = tid; t < ND * 64; t += 512) {
            int j = t >> 6, x = t & 63;
            outb[(size_t)(i * ND + j) * HW + x] = 0.f;
        }
    }

    Stage st;
    stage_issue(st, f1row, xp, cg);
    stage_commit_lds(st, Alds, xp, cg);
    __syncthreads();

    int px  = w & 1;
    int m0  = ((w >> 1) & 1) * 16;
    int n0  = ((w >> 2) & 1) * 16;
    int l15 = lane & 15;
    int kgr = (lane >> 4) * 8;

    short8 afrag[8];
    int arow = 2 * (m0 + l15) + px;
    #pragma unroll
    for (int kk = 0; kk < 8; ++kk)
        afrag[kk] = *reinterpret_cast<const short8*>(
            reinterpret_cast<const char*>(Alds) + swz_off(arow, kk * 32 + kgr));

    int brow = 2 * (n0 + l15) + px;
    int srow = 2 * (m0 + (lane >> 4) * 4) + px;
    int scol = n0 + l15;

    for (int vy = uy - 10; vy <= uy + 10; ++vy) {
        if (vy < 0 || vy >= H2) continue;
        int i  = vy - uy + 10;
        int y2 = 2 * vy + py;
        __syncthreads();
        stage_issue(st, f2base + (size_t)y2 * NW, xp, cg);
        stage_commit_lds(st, Blds, xp, cg);
        __syncthreads();

        f32x4 acc = {0.f, 0.f, 0.f, 0.f};
        #pragma unroll
        for (int kk = 0; kk < 8; ++kk) {
            short8 bfrag = *reinterpret_cast<const short8*>(
                reinterpret_cast<const char*>(Blds) + swz_off(brow, kk * 32 + kgr));
            acc = __builtin_amdgcn_mfma_f32_16x16x32_bf16(afrag[kk], bfrag, acc, 0, 0, 0);
        }
        #pragma unroll
        for (int r = 0; r < 4; ++r)
            Slds[srow + 2 * r][scol] = acc[r] * (1.f / 256.f);
        __syncthreads();

        for (int t = tid; t < ND * 64; t += 512) {
            int j = t >> 6, x = t & 63;
            int vx = (x >> 1) + j - 10;
            float v = ((unsigned)vx < 32u) ? Slds[x][vx] : 0.f;
            outb[(size_t)(i * ND + j) * HW + x] = v;
        }
    }
}

extern "C" void kernel_launch(void* const* d_in, const int* in_sizes, int n_in,
                              void* d_out, int out_size, void* d_ws, size_t ws_size,
                              hipStream_t stream) {
    const float* in1 = (const float*)d_in[0];
    const float* in2 = (const float*)d_in[1];
    float* o = (float*)d_out;
    if (ws_size >= WS_FULL) {
        hipLaunchKernelGGL(prep_kernel, dim3(768), dim3(512), 0, stream, in1, in2, (unsigned short*)d_ws);
        hipLaunchKernelGGL(corr_main3<true>, dim3(768), dim3(512), 0, stream,
                           in1, (const unsigned short*)d_ws, o);
    } else if (ws_size >= WS_F2) {
        hipLaunchKernelGGL(prep_kernel, dim3(384), dim3(512), 0, stream, in1, in2, (unsigned short*)d_ws);
        hipLaunchKernelGGL(corr_main3<false>, dim3(768), dim3(512), 0, stream,
                           in1, (const unsigned short*)d_ws, o);
    } else {
        hipLaunchKernelGGL(corr_fallback, dim3(384), dim3(512), 0, stream, in1, in2, o);
    }
}